// Round 1
// baseline (6973.605 us; speedup 1.0000x reference)
//
#include <hip/hip_runtime.h>
#include <math.h>

#define Nn 50000
#define Ff 16
#define Tt 12
#define Hh 64
#define Ee 1600000
#define Cc 80  // F + H

static __device__ __forceinline__ float sigmoidf_(float x) { return 1.0f / (1.0f + expf(-x)); }

// ---------------- CSR build ----------------
__global__ void k_deg(const int* __restrict__ ei, const float* __restrict__ ew,
                      float* __restrict__ deg, int* __restrict__ cnt) {
  int e = blockIdx.x * blockDim.x + threadIdx.x;
  if (e >= Ee) return;
  int d = ei[Ee + e];
  atomicAdd(&deg[d], ew[e]);
  atomicAdd(&cnt[d], 1);
}

__global__ void k_dis(float* dd) {
  int i = blockIdx.x * blockDim.x + threadIdx.x;
  if (i >= Nn) return;
  dd[i] = 1.0f / sqrtf(dd[i] + 1.0f);  // rsqrt(deg + self-loop)
}

__global__ __launch_bounds__(1024) void k_scan(const int* __restrict__ cnt,
                                               int* __restrict__ rp, int* __restrict__ cur) {
  __shared__ int ss[1024];
  const int ITEMS = (Nn + 1023) / 1024;  // 49
  int t = threadIdx.x;
  int base = t * ITEMS;
  int sum = 0;
  for (int k = 0; k < ITEMS; k++) {
    int idx = base + k;
    if (idx < Nn) sum += cnt[idx];
  }
  ss[t] = sum;
  __syncthreads();
  for (int off = 1; off < 1024; off <<= 1) {
    int v = (t >= off) ? ss[t - off] : 0;
    __syncthreads();
    ss[t] += v;
    __syncthreads();
  }
  int run = ss[t] - sum;  // exclusive prefix
  for (int k = 0; k < ITEMS; k++) {
    int idx = base + k;
    if (idx < Nn) { rp[idx] = run; cur[idx] = run; run += cnt[idx]; }
  }
  if (t == 0) rp[Nn] = Ee;
}

__global__ void k_scatter(const int* __restrict__ ei, const float* __restrict__ ew,
                          const float* __restrict__ dis, int* __restrict__ cur,
                          int* __restrict__ csrc, float* __restrict__ cw) {
  int e = blockIdx.x * blockDim.x + threadIdx.x;
  if (e >= Ee) return;
  int s = ei[e];
  int d = ei[Ee + e];
  float w = ew[e] * dis[s] * dis[d];
  int pos = atomicAdd(&cur[d], 1);
  csrc[pos] = s;
  cw[pos] = w;
}

// ---------------- aggregation (CSR, wave per dst node) ----------------
// Px[t][i][f] = A_hat @ x  for all t at once (x row = 192 contiguous floats)
__global__ __launch_bounds__(256) void k_agg_px(
    const float* __restrict__ x, float* __restrict__ Px,
    const int* __restrict__ rp, const int* __restrict__ csrc,
    const float* __restrict__ cw, const float* __restrict__ dis) {
  int i = blockIdx.x * 4 + (threadIdx.x >> 6);
  if (i >= Nn) return;
  int lane = threadIdx.x & 63;
  const int R = Ff * Tt;  // 192
  float d = dis[i];
  float sn = d * d;
  const float* xi = x + (size_t)i * R;
  float a0 = sn * xi[lane];
  float a1 = sn * xi[64 + lane];
  float a2 = sn * xi[128 + lane];
  int jb = rp[i], je = rp[i + 1];
  for (int j = jb; j < je; j++) {
    int s = csrc[j];
    float w = cw[j];
    const float* xr = x + (size_t)s * R;
    a0 = fmaf(w, xr[lane], a0);
    a1 = fmaf(w, xr[64 + lane], a1);
    a2 = fmaf(w, xr[128 + lane], a2);
  }
#pragma unroll
  for (int k = 0; k < 3; k++) {
    int c = lane + 64 * k;      // c = f*T + t within the x row
    int f = c / Tt, tt = c % Tt;
    float val = (k == 0) ? a0 : (k == 1 ? a1 : a2);
    Px[(size_t)tt * Nn * Ff + (size_t)i * Ff + f] = val;
  }
}

// out[i][:] = self_norm[i]*v[i][:] + sum_edges w*v[src][:]   (64 channels, lane=channel)
__global__ __launch_bounds__(256) void k_agg64(
    const float* __restrict__ v, float* __restrict__ outv,
    const int* __restrict__ rp, const int* __restrict__ csrc,
    const float* __restrict__ cw, const float* __restrict__ dis) {
  int i = blockIdx.x * 4 + (threadIdx.x >> 6);
  if (i >= Nn) return;
  int o = threadIdx.x & 63;
  float d = dis[i];
  float acc = d * d * v[(size_t)i * Hh + o];
  int jb = rp[i], je = rp[i + 1];
  for (int j = jb; j < je; j++) {
    int s = csrc[j];
    float w = cw[j];
    acc = fmaf(w, v[(size_t)s * Hh + o], acc);
  }
  outv[(size_t)i * Hh + o] = acc;
}

// ---------------- GEMM z/r:  z=sig(Xagg@Wz+bz), rh=sig(Xagg@Wr+br)*h ----------------
__global__ __launch_bounds__(256) void k_gemm_zr(
    const float* __restrict__ Px, const float* __restrict__ Ph,
    const float* __restrict__ h,
    const float* __restrict__ Wz, const float* __restrict__ bz,
    const float* __restrict__ Wr, const float* __restrict__ br,
    float* __restrict__ zb, float* __restrict__ rhb, int tstep) {
  __shared__ float sWz[Cc * Hh];
  __shared__ float sWr[Cc * Hh];
  __shared__ float sX[32 * Cc];
  const int tid = threadIdx.x;
  const int i0 = blockIdx.x * 32;
  {
    const float4* w4z = (const float4*)Wz;
    const float4* w4r = (const float4*)Wr;
    float4* s4z = (float4*)sWz;
    float4* s4r = (float4*)sWr;
    for (int q = tid; q < (Cc * Hh) / 4; q += 256) { s4z[q] = w4z[q]; s4r[q] = w4r[q]; }
  }
  {
    float4* s4 = (float4*)sX;
    const float4* px4 = (const float4*)(Px + (size_t)tstep * Nn * Ff);
    const float4* ph4 = (const float4*)Ph;
    for (int q = tid; q < 32 * 20; q += 256) {
      int n = q / 20, r = q % 20;
      int i = i0 + n;
      float4 v = make_float4(0.f, 0.f, 0.f, 0.f);
      if (i < Nn) v = (r < 4) ? px4[(size_t)i * 4 + r] : ph4[(size_t)i * 16 + (r - 4)];
      s4[q] = v;
    }
  }
  __syncthreads();
  const int o = tid & 63;
  const int grp = tid >> 6;
  float az[8], ar[8];
#pragma unroll
  for (int j = 0; j < 8; j++) { az[j] = 0.f; ar[j] = 0.f; }
  for (int c = 0; c < Cc; c += 4) {
    float wz0 = sWz[(c + 0) * Hh + o], wz1 = sWz[(c + 1) * Hh + o];
    float wz2 = sWz[(c + 2) * Hh + o], wz3 = sWz[(c + 3) * Hh + o];
    float wr0 = sWr[(c + 0) * Hh + o], wr1 = sWr[(c + 1) * Hh + o];
    float wr2 = sWr[(c + 2) * Hh + o], wr3 = sWr[(c + 3) * Hh + o];
#pragma unroll
    for (int j = 0; j < 8; j++) {
      const float4 xv = *(const float4*)&sX[(grp * 8 + j) * Cc + c];
      az[j] = fmaf(xv.x, wz0, fmaf(xv.y, wz1, fmaf(xv.z, wz2, fmaf(xv.w, wz3, az[j]))));
      ar[j] = fmaf(xv.x, wr0, fmaf(xv.y, wr1, fmaf(xv.z, wr2, fmaf(xv.w, wr3, ar[j]))));
    }
  }
  float bzo = bz[o], bro = br[o];
#pragma unroll
  for (int j = 0; j < 8; j++) {
    int i = i0 + grp * 8 + j;
    if (i < Nn) {
      float zv = sigmoidf_(az[j] + bzo);
      float rv = sigmoidf_(ar[j] + bro);
      float hv = h[(size_t)i * Hh + o];
      zb[(size_t)i * Hh + o] = zv;
      rhb[(size_t)i * Hh + o] = rv * hv;
    }
  }
}

// ---------------- GEMM h: hc=tanh(Xagg@Wh+bh); h=z*h+(1-z)*hc; fused attention ----------------
__global__ __launch_bounds__(256) void k_gemm_h(
    const float* __restrict__ Px, const float* __restrict__ Prh,
    const float* __restrict__ zb, float* __restrict__ h,
    const float* __restrict__ Wh, const float* __restrict__ bh,
    const float* __restrict__ Wa, const float* __restrict__ ba,
    const float* __restrict__ cv,
    float* __restrict__ mbuf, float* __restrict__ sbuf, float* __restrict__ ctx,
    int tstep) {
  __shared__ float sWh[Cc * Hh];  // 5120
  __shared__ float sWa[Hh * Hh];  // 4096
  __shared__ float sX[32 * Cc];   // 2560
  __shared__ float sHn[32 * Hh];  // 2048
  const int tid = threadIdx.x;
  const int i0 = blockIdx.x * 32;
  {
    const float4* w4 = (const float4*)Wh;
    float4* s4 = (float4*)sWh;
    for (int q = tid; q < (Cc * Hh) / 4; q += 256) s4[q] = w4[q];
    const float4* a4 = (const float4*)Wa;
    float4* sa4 = (float4*)sWa;
    for (int q = tid; q < (Hh * Hh) / 4; q += 256) sa4[q] = a4[q];
  }
  {
    float4* s4 = (float4*)sX;
    const float4* px4 = (const float4*)(Px + (size_t)tstep * Nn * Ff);
    const float4* ph4 = (const float4*)Prh;
    for (int q = tid; q < 32 * 20; q += 256) {
      int n = q / 20, r = q % 20;
      int i = i0 + n;
      float4 v = make_float4(0.f, 0.f, 0.f, 0.f);
      if (i < Nn) v = (r < 4) ? px4[(size_t)i * 4 + r] : ph4[(size_t)i * 16 + (r - 4)];
      s4[q] = v;
    }
  }
  __syncthreads();
  const int o = tid & 63;
  const int grp = tid >> 6;
  float ah[8];
#pragma unroll
  for (int j = 0; j < 8; j++) ah[j] = 0.f;
  for (int c = 0; c < Cc; c += 4) {
    float w0 = sWh[(c + 0) * Hh + o], w1 = sWh[(c + 1) * Hh + o];
    float w2 = sWh[(c + 2) * Hh + o], w3 = sWh[(c + 3) * Hh + o];
#pragma unroll
    for (int j = 0; j < 8; j++) {
      const float4 xv = *(const float4*)&sX[(grp * 8 + j) * Cc + c];
      ah[j] = fmaf(xv.x, w0, fmaf(xv.y, w1, fmaf(xv.z, w2, fmaf(xv.w, w3, ah[j]))));
    }
  }
  float bho = bh[o];
#pragma unroll
  for (int j = 0; j < 8; j++) {
    int n = grp * 8 + j;
    int i = i0 + n;
    float hn = 0.f;
    if (i < Nn) {
      float hc = tanhf(ah[j] + bho);
      float zv = zb[(size_t)i * Hh + o];
      float hv = h[(size_t)i * Hh + o];
      hn = zv * hv + (1.0f - zv) * hc;
      h[(size_t)i * Hh + o] = hn;
    }
    sHn[n * Hh + o] = hn;
  }
  __syncthreads();
  // attention: score = tanh(hn @ Wa + ba); align = score . cv; online softmax into (m,s,ctx)
  float bao = ba[o];
  float cvo = cv[o];
  for (int j = 0; j < 8; j++) {
    int n = grp * 8 + j;
    int i = i0 + n;
    float sp = 0.f;
    for (int c = 0; c < Hh; c += 4) {
      const float4 hv4 = *(const float4*)&sHn[n * Hh + c];
      sp = fmaf(hv4.x, sWa[(c + 0) * Hh + o],
           fmaf(hv4.y, sWa[(c + 1) * Hh + o],
           fmaf(hv4.z, sWa[(c + 2) * Hh + o],
           fmaf(hv4.w, sWa[(c + 3) * Hh + o], sp))));
    }
    float sc = tanhf(sp + bao);
    float ap = sc * cvo;
#pragma unroll
    for (int off = 32; off >= 1; off >>= 1) ap += __shfl_xor(ap, off, 64);
    // ap = align[i][t], identical on all lanes
    if (i < Nn) {
      if (tstep == 0) {
        ctx[(size_t)i * Hh + o] = sHn[n * Hh + o];
        if (o == 0) { mbuf[i] = ap; sbuf[i] = 1.0f; }
      } else {
        float mo = mbuf[i];
        float so = sbuf[i];
        float mn = fmaxf(mo, ap);
        float scale = expf(mo - mn);
        float p = expf(ap - mn);
        ctx[(size_t)i * Hh + o] = ctx[(size_t)i * Hh + o] * scale + p * sHn[n * Hh + o];
        if (o == 0) { mbuf[i] = mn; sbuf[i] = so * scale + p; }
      }
    }
  }
}

// ---------------- output: out[i] = (ctx/s) . Wfc + bfc ----------------
__global__ __launch_bounds__(256) void k_out(
    const float* __restrict__ ctx, const float* __restrict__ sbuf,
    const float* __restrict__ Wfc, const float* __restrict__ bfc,
    float* __restrict__ out) {
  int i = blockIdx.x * 4 + (threadIdx.x >> 6);
  if (i >= Nn) return;
  int o = threadIdx.x & 63;
  float inv = 1.0f / sbuf[i];
  float p = ctx[(size_t)i * Hh + o] * inv * Wfc[o];
#pragma unroll
  for (int off = 32; off >= 1; off >>= 1) p += __shfl_xor(p, off, 64);
  if (o == 0) out[i] = p + bfc[0];
}

extern "C" void kernel_launch(void* const* d_in, const int* in_sizes, int n_in,
                              void* d_out, int out_size, void* d_ws, size_t ws_size,
                              hipStream_t stream) {
  const float* x   = (const float*)d_in[0];
  const int* ei    = (const int*)d_in[1];
  const float* ew  = (const float*)d_in[2];
  const float* Wz  = (const float*)d_in[3];
  const float* bz  = (const float*)d_in[4];
  const float* Wr  = (const float*)d_in[5];
  const float* br  = (const float*)d_in[6];
  const float* Wh  = (const float*)d_in[7];
  const float* bh  = (const float*)d_in[8];
  const float* Wa  = (const float*)d_in[9];
  const float* ba  = (const float*)d_in[10];
  const float* cv  = (const float*)d_in[11];
  const float* Wfc = (const float*)d_in[12];
  const float* bfc = (const float*)d_in[13];
  float* out = (float*)d_out;

  char* w = (char*)d_ws;
  auto alloc = [&](size_t bytes) {
    char* p = w;
    w += (bytes + 255) & ~(size_t)255;
    return p;
  };
  float* dis = (float*)alloc((size_t)Nn * 4);       // deg, then rsqrt in place
  int* cnt   = (int*)alloc((size_t)Nn * 4);
  int* rp    = (int*)alloc((size_t)(Nn + 1) * 4);
  int* cur   = (int*)alloc((size_t)Nn * 4);
  int* csrc  = (int*)alloc((size_t)Ee * 4);
  float* cw  = (float*)alloc((size_t)Ee * 4);
  float* Pxb = (float*)alloc((size_t)Tt * Nn * Ff * 4);
  float* h   = (float*)alloc((size_t)Nn * Hh * 4);
  float* zbf = (float*)alloc((size_t)Nn * Hh * 4);
  float* rhb = (float*)alloc((size_t)Nn * Hh * 4);
  float* Ph  = (float*)alloc((size_t)Nn * Hh * 4);
  float* Prh = (float*)alloc((size_t)Nn * Hh * 4);
  float* mb  = (float*)alloc((size_t)Nn * 4);
  float* sb  = (float*)alloc((size_t)Nn * 4);
  float* ctx = (float*)alloc((size_t)Nn * Hh * 4);

  hipMemsetAsync(dis, 0, (size_t)Nn * 4, stream);
  hipMemsetAsync(cnt, 0, (size_t)Nn * 4, stream);
  hipMemsetAsync(h, 0, (size_t)Nn * Hh * 4, stream);

  k_deg<<<(Ee + 255) / 256, 256, 0, stream>>>(ei, ew, dis, cnt);
  k_dis<<<(Nn + 255) / 256, 256, 0, stream>>>(dis);
  k_scan<<<1, 1024, 0, stream>>>(cnt, rp, cur);
  k_scatter<<<(Ee + 255) / 256, 256, 0, stream>>>(ei, ew, dis, cur, csrc, cw);
  k_agg_px<<<(Nn + 3) / 4, 256, 0, stream>>>(x, Pxb, rp, csrc, cw, dis);

  const int gGemm = (Nn + 31) / 32;
  const int gNode = (Nn + 3) / 4;
  for (int t = 0; t < Tt; t++) {
    k_agg64<<<gNode, 256, 0, stream>>>(h, Ph, rp, csrc, cw, dis);
    k_gemm_zr<<<gGemm, 256, 0, stream>>>(Pxb, Ph, h, Wz, bz, Wr, br, zbf, rhb, t);
    k_agg64<<<gNode, 256, 0, stream>>>(rhb, Prh, rp, csrc, cw, dis);
    k_gemm_h<<<gGemm, 256, 0, stream>>>(Pxb, Prh, zbf, h, Wh, bh, Wa, ba, cv, mb, sb, ctx, t);
  }
  k_out<<<gNode, 256, 0, stream>>>(ctx, sb, Wfc, bfc, out);
}